// Round 13
// baseline (231.094 us; speedup 1.0000x reference)
//
#include <hip/hip_runtime.h>
#include <stdint.h>

typedef _Float16 half8 __attribute__((ext_vector_type(8)));
typedef float float4v __attribute__((ext_vector_type(4)));

#define C_IN 64
#define H_IN 256
#define W_IN 256
#define H_OUT 254
#define W_OUT 254
#define T_ROWS 6
#define T_COLS 68
#define A_ROWS (T_ROWS * T_COLS)   // 408 LDS rows of 64 fp16 (128 B)

// ---------------------------------------------------------------------------
// Pack conv_weight (OIHW fp32) into coalesced-fragment layout (v5 layout):
//   Bp2[g][co][q][e]  with g = (kh*3+kw)*2 + h,  cin = h*32 + q*8 + e
// One wave's fragment load (16 co x 4 q x 8 e) = 1 KB contiguous, L2-hot.
// ---------------------------------------------------------------------------
__global__ void pack_w_kernel(const float* __restrict__ w, _Float16* __restrict__ Bp2) {
    int idx = blockIdx.x * 256 + threadIdx.x;          // 128*576 = 73728
    if (idx >= 128 * 576) return;
    int co  = idx / 576;
    int kp  = idx - co * 576;
    int tap = kp >> 6;
    int cin = kp & 63;
    int kh  = tap / 3, kw = tap - kh * 3;
    int h   = cin >> 5;
    int q   = (cin >> 3) & 3;
    int e   = cin & 7;
    int g   = tap * 2 + h;
    Bp2[((((size_t)g * 128 + co) * 4) + q) * 8 + e] =
        (_Float16)w[(co * 64 + cin) * 9 + kh * 3 + kw];
}

// ---------------------------------------------------------------------------
// v13 = v5 structure (fused transpose-stage, B from L2 coalesced, NO in-loop
// barriers, 4 waves x 128px x 64co, 2 waves/SIMD) + PINNED depth-1 A&B
// register double-buffer (v10 proved SGB pinning materializes the prefetch;
// at 2 waves/SIMD the 256-reg budget fits acc128 + Adbuf64 + Bdbuf32).
// Waves free-run across the 18 groups; LDS (1152), L2-B (585) and MFMA
// (1242/SIMD) pipes overlap per slot instead of alternating.
// grid (4, 64, 16), 256 thr.
// ---------------------------------------------------------------------------
__global__ __launch_bounds__(256, 2)
void conv_v13_kernel(const float* __restrict__ x,
                     const _Float16* __restrict__ Bp2,
                     const float* __restrict__ bias,
                     float* __restrict__ out) {
    __shared__ __align__(16) _Float16 Alds[A_ROWS * 64];   // 52224 B
    __shared__ float minbuf[2][256];

    const int tid  = threadIdx.x;
    const int lane = tid & 63;
    const int wave = tid >> 6;
    const int ow0  = blockIdx.x * 64;
    const int oh0  = blockIdx.y * 4;
    const int nb   = blockIdx.z;

    // ---- fused transpose-stage: x NCHW fp32 -> Alds[px][cin] fp16 (swizzled)
    {
        const float* xb = x + (size_t)nb * (C_IN * H_IN * W_IN);
        for (int id = tid; id < 816; id += 256) {
            int cinoct = (unsigned)id / 102u;
            int pxq    = id - cinoct * 102;
            int row0   = pxq * 4;
            int r      = (unsigned)row0 / (unsigned)T_COLS;
            int c      = row0 - r * T_COLS;
            int ih     = oh0 + r; if (ih > H_IN - 1) ih = H_IN - 1;
            int iw     = ow0 + c; if (iw > W_IN - 4) iw = W_IN - 4;
            const float* src = xb + ((size_t)(cinoct * 8) * (H_IN * W_IN))
                                  + (size_t)ih * W_IN + iw;
            float4v f[8];
#pragma unroll
            for (int u = 0; u < 8; ++u)
                f[u] = *(const float4v*)(src + (size_t)u * (H_IN * W_IN));
#pragma unroll
            for (int j = 0; j < 4; ++j) {
                int row = row0 + j;
                half8 hv;
#pragma unroll
                for (int u = 0; u < 8; ++u) hv[u] = (_Float16)f[u][j];
                *(half8*)((char*)Alds + row * 128
                          + ((cinoct * 16) ^ ((row & 7) << 4))) = hv;
            }
        }
    }
    __syncthreads();

    const int wr = wave >> 1;       // px half: 0 -> px 0..127, 1 -> 128..255
    const int wc = wave & 1;        // co half
    const int q  = lane >> 4;
    const int lr = lane & 15;

    float4v acc[8][4];
#pragma unroll
    for (int m = 0; m < 8; ++m)
#pragma unroll
        for (int n = 0; n < 4; ++n)
#pragma unroll
            for (int i = 0; i < 4; ++i) acc[m][n][i] = 0.0f;

    const char* bp0 = (const char*)Bp2 + (size_t)(wc * 64 + lr) * 64 + q * 16;

    // frag loaders (gg is unroll-time constant at all call sites)
    auto loadA = [&](int gg, half8 (&dst)[8]) {
        const int tap = gg >> 1, hh = gg & 1;
        const int kh = tap / 3, kw = tap - kh * 3;
        const int kb = hh * 64 + q * 16;
#pragma unroll
        for (int m = 0; m < 8; ++m) {
            int row = (wr * 2 + (m >> 2) + kh) * T_COLS + (m & 3) * 16 + lr + kw;
            dst[m] = *(const half8*)((const char*)Alds + row * 128
                                     + (kb ^ ((row & 7) << 4)));
        }
    };
    auto loadB = [&](int gg, half8 (&dst)[4]) {
#pragma unroll
        for (int n = 0; n < 4; ++n)
            dst[n] = *(const half8*)(bp0 + (size_t)gg * 8192 + n * 1024);
    };

    half8 acur[8], anxt[8], bcur[4], bnxt[4];
    loadA(0, acur);
    loadB(0, bcur);

#pragma unroll
    for (int g = 0; g < 18; ++g) {
        // ---- depth-1 prefetch of group g+1 into the other named set
        if (g < 17) {
            if (g & 1) { loadB(g + 1, bcur); loadA(g + 1, acur); }
            else       { loadB(g + 1, bnxt); loadA(g + 1, anxt); }
        }
        // pin emission: 4 B global loads + 8 A ds_reads ahead of the MFMAs
        __builtin_amdgcn_sched_group_barrier(0x020, 4, 0);   // VMEM_READ x4
        __builtin_amdgcn_sched_group_barrier(0x100, 8, 0);   // DS_READ x8

        half8 (&A)[8] = (g & 1) ? anxt : acur;
        half8 (&B)[4] = (g & 1) ? bnxt : bcur;

        __builtin_amdgcn_s_setprio(1);
#pragma unroll
        for (int m = 0; m < 8; ++m)
#pragma unroll
            for (int n = 0; n < 4; ++n)
                acc[m][n] = __builtin_amdgcn_mfma_f32_16x16x32_f16(
                    A[m], B[n], acc[m][n], 0, 0, 0);
        __builtin_amdgcn_s_setprio(0);
        __builtin_amdgcn_sched_group_barrier(0x8, 32, 0);    // MFMA x32
    }

    // ---- epilogue: + bias, min over channels, double tanh
#pragma unroll
    for (int m = 0; m < 8; ++m) {
        float4v v;
#pragma unroll
        for (int n = 0; n < 4; ++n) {
            float bv = bias[wc * 64 + n * 16 + lr];
#pragma unroll
            for (int i = 0; i < 4; ++i) {
                float t = acc[m][n][i] + bv;
                v[i] = (n == 0) ? t : fminf(v[i], t);
            }
        }
#pragma unroll
        for (int off = 1; off < 16; off <<= 1)
#pragma unroll
            for (int i = 0; i < 4; ++i)
                v[i] = fminf(v[i], __shfl_xor(v[i], off, 64));
        if (lr == 0) {
#pragma unroll
            for (int i = 0; i < 4; ++i)
                minbuf[wc][wr * 128 + m * 16 + q * 4 + i] = v[i];
        }
    }
    __syncthreads();

    {
        int r = tid >> 6, c = tid & 63;
        int oh = oh0 + r, ow = ow0 + c;
        if (oh < H_OUT && ow < W_OUT) {
            float mv = fminf(minbuf[0][tid], minbuf[1][tid]);
            out[((size_t)nb * H_OUT + oh) * W_OUT + ow] = tanhf(tanhf(mv));
        }
    }
}

extern "C" void kernel_launch(void* const* d_in, const int* in_sizes, int n_in,
                              void* d_out, int out_size, void* d_ws, size_t ws_size,
                              hipStream_t stream) {
    const float* x    = (const float*)d_in[0];
    const float* w    = (const float*)d_in[1];
    const float* bias = (const float*)d_in[2];
    float* out        = (float*)d_out;
    _Float16* Bp2     = (_Float16*)d_ws;   // 147456 B

    pack_w_kernel<<<dim3(288), dim3(256), 0, stream>>>(w, Bp2);
    conv_v13_kernel<<<dim3(4, 64, 16), dim3(256), 0, stream>>>(x, Bp2, bias, out);
}